// Round 17
// baseline (359.346 us; speedup 1.0000x reference)
//
#include <hip/hip_runtime.h>
#include <hip/hip_bf16.h>

#define NN 20000
#define NE 320000
#define MPAD 20096   // 157 * 128
#define ORD 1024     // rows used by the pooling head (order+1; order fixed = 1023)
#define NB 79        // ceil(NN/256) node blocks for the CSR scan

typedef __hip_bfloat16 bf16;
typedef __attribute__((ext_vector_type(8))) short bf16x8;
typedef __attribute__((ext_vector_type(4))) float f32x4;

static __device__ __forceinline__ float b2f(bf16 x) { return __bfloat162float(x); }
static __device__ __forceinline__ float bfbits2f(short s) {
    unsigned int u = ((unsigned int)(unsigned short)s) << 16;
    float f; __builtin_memcpy(&f, &u, 4); return f;
}
static __device__ __forceinline__ short f2bfbits(float v) {
    bf16 h = __float2bfloat16(v);
    short s; __builtin_memcpy(&s, &h, 2); return s;
}
static __device__ __forceinline__ unsigned short f2bfu(float v) {
    bf16 h = __float2bfloat16(v);
    unsigned short s; __builtin_memcpy(&s, &h, 2); return s;
}

// ---------------- setup: wal/war (blocks 0..959) + convert/transpose/counts/h (960+)
__global__ void setup_all(const float* __restrict__ feat,
                          const float* __restrict__ W1, const float* __restrict__ al1, const float* __restrict__ ar1,
                          const float* __restrict__ W2, const float* __restrict__ al2, const float* __restrict__ ar2,
                          const float* __restrict__ W3, const float* __restrict__ al3, const float* __restrict__ ar3,
                          const float* __restrict__ W4, const float* __restrict__ al4, const float* __restrict__ ar4,
                          bf16* __restrict__ featb, bf16* __restrict__ wt1,
                          bf16* __restrict__ wt2, bf16* __restrict__ wt3,
                          bf16* __restrict__ wt4, int* __restrict__ counts,
                          int* __restrict__ hglob,
                          float* __restrict__ walbuf, float* __restrict__ warbuf) {
    int b = blockIdx.x;
    if (b < 960) {
        const float *W, *al, *ar; int dout, k; float *wal, *war;
        if (b < 64)       { W = W1; al = al1; ar = ar1; dout = 128;  k = b;       wal = walbuf;        war = warbuf; }
        else if (b < 192) { W = W2; al = al2; ar = ar2; dout = 256;  k = b - 64;  wal = walbuf + 512;  war = warbuf + 512; }
        else if (b < 448) { W = W3; al = al3; ar = ar3; dout = 512;  k = b - 192; wal = walbuf + 1024; war = warbuf + 1024; }
        else              { W = W4; al = al4; ar = ar4; dout = 1024; k = b - 448; wal = walbuf + 1536; war = warbuf + 1536; }
        const float* row = W + (long)k * dout;
        float sl = 0.f, sr = 0.f;
        for (int j = threadIdx.x; j < dout; j += 256) {
            float w = row[j];
            sl += w * al[j];
            sr += w * ar[j];
        }
        __shared__ float sbl[256], sbr[256];
        sbl[threadIdx.x] = sl; sbr[threadIdx.x] = sr;
        __syncthreads();
        for (int st = 128; st > 0; st >>= 1) {
            if (threadIdx.x < st) {
                sbl[threadIdx.x] += sbl[threadIdx.x + st];
                sbr[threadIdx.x] += sbr[threadIdx.x + st];
            }
            __syncthreads();
        }
        if (threadIdx.x == 0) { wal[k] = sbl[0]; war[k] = sbr[0]; }
        return;
    }
    int i = (b - 960) * 256 + threadIdx.x;
    if (i < NN) counts[i] = 0;
    if (i < 256) hglob[i] = 0;
    if (i < 1280000) { featb[i] = __float2bfloat16(feat[i]); return; }
    i -= 1280000;
    if (i < 8192)  { int r = i >> 7,  c = i & 127;  wt1[c * 64 + r]  = __float2bfloat16(W1[i]); return; }
    i -= 8192;
    if (i < 32768) { int r = i >> 8,  c = i & 255;  wt2[c * 128 + r] = __float2bfloat16(W2[i]); return; }
    i -= 32768;
    if (i < 131072){ int r = i >> 9,  c = i & 511;  wt3[c * 256 + r] = __float2bfloat16(W3[i]); return; }
    i -= 131072;
    if (i < 524288){ int r = i >> 10, c = i & 1023; wt4[c * 512 + r] = __float2bfloat16(W4[i]); return; }
}

// ---------------- CSR hist ----------------
__global__ void hist_kernel(const int* __restrict__ dst, int* __restrict__ counts, int n) {
    int i = blockIdx.x * blockDim.x + threadIdx.x;
    if (i < n) atomicAdd(&counts[dst[i]], 1);
}

// ---------------- CSR phase1 (WIDE, r16 lesson: 1-block scan_sort = 48 us on
// one CU): per-block count sums + degree histogram ----------------
__global__ void csr_phase1(const int* __restrict__ counts, int* __restrict__ blocksums,
                           int* __restrict__ hglob) {
    __shared__ int sb[256];
    __shared__ int hh[256];
    int tid = threadIdx.x;
    hh[tid] = 0;
    int i = blockIdx.x * 256 + tid;
    int c = (i < NN) ? counts[i] : 0;
    sb[tid] = c;
    __syncthreads();
    for (int st = 128; st > 0; st >>= 1) {
        if (tid < st) sb[tid] += sb[tid + st];
        __syncthreads();
    }
    if (tid == 0) blocksums[blockIdx.x] = sb[0];
    if (i < NN) {
        int d = c > 255 ? 255 : c;
        atomicAdd(&hh[d], 1);
    }
    __syncthreads();
    if (hh[tid] > 0) atomicAdd(&hglob[tid], hh[tid]);
}

// ---------------- CSR phase2 (WIDE): blocks 0..NB-1 write offsets/cursor
// (each block redundantly scans the tiny blocksums array); block NB scans the
// degree histogram into the bucket cursors ----------------
__global__ void csr_phase2(const int* __restrict__ counts, const int* __restrict__ blocksums,
                           int* __restrict__ offsets, int* __restrict__ cursor,
                           const int* __restrict__ hglob, int* __restrict__ curg) {
    int tid = threadIdx.x;
    if (blockIdx.x == NB) {
        // exclusive scan of hglob[256] -> curg (degree-bucket start cursors)
        __shared__ int hs[256];
        int orig = hglob[tid];
        hs[tid] = orig;
        __syncthreads();
        for (int st = 1; st < 256; st <<= 1) {
            int u = (tid >= st) ? hs[tid - st] : 0;
            __syncthreads();
            hs[tid] += u;
            __syncthreads();
        }
        curg[tid] = hs[tid] - orig;
        return;
    }
    __shared__ int bs[256];
    bs[tid] = (tid < NB) ? blocksums[tid] : 0;
    __syncthreads();
    for (int st = 1; st < 256; st <<= 1) {
        int u = (tid >= st) ? bs[tid - st] : 0;
        __syncthreads();
        bs[tid] += u;
        __syncthreads();
    }
    int base = (blockIdx.x == 0) ? 0 : bs[blockIdx.x - 1];
    __shared__ int sc[256];
    int i = blockIdx.x * 256 + tid;
    int c = (i < NN) ? counts[i] : 0;
    sc[tid] = c;
    __syncthreads();
    for (int st = 1; st < 256; st <<= 1) {
        int u = (tid >= st) ? sc[tid - st] : 0;
        __syncthreads();
        sc[tid] += u;
        __syncthreads();
    }
    int excl = base + sc[tid] - c;
    if (i < NN) { offsets[i] = excl; cursor[i] = excl; }
    if (i == NN - 1) offsets[NN] = excl + c;
}

// ---------------- scatter (0..1249) + perm scatter (1250..1328) + L1 el/er (1329+)
// Perm: within-degree-bucket order nondeterministic — irrelevant (r4: per-node
// CSR accumulation order unchanged -> bit-identical).
__global__ void scatter_elr(const int* __restrict__ src, const int* __restrict__ dst,
                            int* __restrict__ cursor, int* __restrict__ esrc,
                            const int* __restrict__ counts, int* __restrict__ curg,
                            int* __restrict__ nodeperm,
                            const bf16* __restrict__ X, const float* __restrict__ wal,
                            const float* __restrict__ war, float* __restrict__ el,
                            float* __restrict__ er) {
    int b = blockIdx.x;
    if (b < 1250) {
        int i = b * 256 + threadIdx.x;   // 1250*256 = 320000 = NE exactly
        int p = atomicAdd(&cursor[dst[i]], 1);
        esrc[p] = src[i];
        return;
    }
    if (b < 1250 + NB) {
        int i = (b - 1250) * 256 + threadIdx.x;
        if (i < NN) {
            int d = counts[i]; if (d > 255) d = 255;
            int p = atomicAdd(&curg[d], 1);
            nodeperm[p] = i;
        }
        return;
    }
    int idx = (b - 1250 - NB) * 256 + threadIdx.x;
    int node = idx >> 6;
    int lane = threadIdx.x & 63;
    if (node >= NN) return;
    float x = bfbits2f(*((const short*)X + (long)node * 64 + lane));
    float sl = x * wal[lane];
    float sr = x * war[lane];
    #pragma unroll
    for (int o = 32; o > 0; o >>= 1) {
        sl += __shfl_down(sl, o);
        sr += __shfl_down(sr, o);
    }
    if (lane == 0) { el[node] = sl; er[node] = sr; }
}

// ---------------- edge softmax: WAVE per node, lanes parallel over edges.
// Each alpha computed exactly ONCE (r12 lesson). Natural node order (r8 lesson).
__global__ void edge_softmax_w(const int* __restrict__ off, const int* __restrict__ esrc,
                               const float* __restrict__ el, const float* __restrict__ er,
                               float* __restrict__ alpha, int n) {
    int node = blockIdx.x * 4 + (threadIdx.x >> 6);
    if (node >= n) return;
    int lane = threadIdx.x & 63;
    int s = off[node], e = off[node + 1];
    int deg = e - s;
    if (deg <= 0) return;
    float erd = er[node];
    if (deg <= 64) {
        float v = -1e30f;
        if (lane < deg) {
            float t = el[esrc[s + lane]] + erd;
            v = t >= 0.f ? t : 0.2f * t;
        }
        float mx = v;
        #pragma unroll
        for (int o = 32; o > 0; o >>= 1) mx = fmaxf(mx, __shfl_xor(mx, o));
        float x = (lane < deg) ? __expf(v - mx) : 0.f;
        float ssum = x;
        #pragma unroll
        for (int o = 32; o > 0; o >>= 1) ssum += __shfl_xor(ssum, o);
        if (lane < deg) alpha[s + lane] = x / ssum;
    } else if (deg <= 256) {
        float v[4];
        float mx = -1e30f;
        #pragma unroll
        for (int r = 0; r < 4; r++) {
            v[r] = -1e30f;
            if (r * 64 + lane < deg) {
                float t = el[esrc[s + r * 64 + lane]] + erd;
                v[r] = t >= 0.f ? t : 0.2f * t;
            }
            mx = fmaxf(mx, v[r]);
        }
        #pragma unroll
        for (int o = 32; o > 0; o >>= 1) mx = fmaxf(mx, __shfl_xor(mx, o));
        float ssum = 0.f;
        #pragma unroll
        for (int r = 0; r < 4; r++) {
            v[r] = (r * 64 + lane < deg) ? __expf(v[r] - mx) : 0.f;
            ssum += v[r];
        }
        #pragma unroll
        for (int o = 32; o > 0; o >>= 1) ssum += __shfl_xor(ssum, o);
        float inv = 1.f / ssum;
        #pragma unroll
        for (int r = 0; r < 4; r++)
            if (r * 64 + lane < deg) alpha[s + r * 64 + lane] = v[r] * inv;
    } else if (lane == 0) {
        float mx = -1e30f;
        for (int j = s; j < e; j++) {
            float t = el[esrc[j]] + erd;
            t = t >= 0.f ? t : 0.2f * t;
            alpha[j] = t;
            mx = fmaxf(mx, t);
        }
        float ssum = 0.f;
        for (int j = s; j < e; j++) { float x = __expf(alpha[j] - mx); alpha[j] = x; ssum += x; }
        float inv = 1.f / ssum;
        for (int j = s; j < e; j++) alpha[j] *= inv;
    }
}

// ---------------- Y = A @ X, 64-ch chunks: eighth-wave (8 lanes x 16B) per node.
// chunk = blockIdx LSBs pins each 2.5MB X-slice to one XCD L2 (r8).
// 8-way edge unroll = 8x MLP on the ~200cy L2 chain (r13).
// perm==nullptr -> natural node order (1024-node last layer).
// Also zeros zbuf[0:zn) — producer-side zeroing.
__global__ void aggregate_e(const bf16* __restrict__ X, const float* __restrict__ alpha,
                            const int* __restrict__ esrc, const int* __restrict__ off,
                            const int* __restrict__ perm, float* __restrict__ zbuf, int zn,
                            bf16* __restrict__ Y, int din, int log2chunks, int nmax) {
    {
        int z = blockIdx.x * 256 + threadIdx.x;
        if (z < zn) zbuf[z] = 0.f;
    }
    int chunk = blockIdx.x & ((1 << log2chunks) - 1);
    int nb = blockIdx.x >> log2chunks;
    int sub = threadIdx.x >> 3, sl = threadIdx.x & 7;
    int slot = nb * 32 + sub;
    if (slot >= nmax) return;
    int node = perm ? perm[slot] : slot;
    const short* xb = (const short*)X + chunk * 64 + sl * 8;
    float acc[8] = {0.f,0.f,0.f,0.f,0.f,0.f,0.f,0.f};
    int s = off[node], e = off[node + 1];
    int j = s;
    for (; j + 8 <= e; j += 8) {
        float a[8]; int r[8]; bf16x8 w[8];
        #pragma unroll
        for (int q = 0; q < 8; q++) { a[q] = alpha[j + q]; r[q] = esrc[j + q]; }
        #pragma unroll
        for (int q = 0; q < 8; q++) w[q] = *(const bf16x8*)(xb + (long)r[q] * din);
        #pragma unroll
        for (int q = 0; q < 8; q++)
            #pragma unroll
            for (int v = 0; v < 8; v++) acc[v] += a[q] * bfbits2f(w[q][v]);
    }
    for (; j + 4 <= e; j += 4) {
        float a0 = alpha[j],     a1 = alpha[j + 1];
        float a2 = alpha[j + 2], a3 = alpha[j + 3];
        int r0 = esrc[j],     r1 = esrc[j + 1];
        int r2 = esrc[j + 2], r3 = esrc[j + 3];
        bf16x8 w0 = *(const bf16x8*)(xb + (long)r0 * din);
        bf16x8 w1 = *(const bf16x8*)(xb + (long)r1 * din);
        bf16x8 w2 = *(const bf16x8*)(xb + (long)r2 * din);
        bf16x8 w3 = *(const bf16x8*)(xb + (long)r3 * din);
        #pragma unroll
        for (int v = 0; v < 8; v++) acc[v] += a0 * bfbits2f(w0[v]);
        #pragma unroll
        for (int v = 0; v < 8; v++) acc[v] += a1 * bfbits2f(w1[v]);
        #pragma unroll
        for (int v = 0; v < 8; v++) acc[v] += a2 * bfbits2f(w2[v]);
        #pragma unroll
        for (int v = 0; v < 8; v++) acc[v] += a3 * bfbits2f(w3[v]);
    }
    for (; j < e; j++) {
        float a = alpha[j];
        bf16x8 w = *(const bf16x8*)(xb + (long)esrc[j] * din);
        #pragma unroll
        for (int v = 0; v < 8; v++) acc[v] += a * bfbits2f(w[v]);
    }
    short outv[8];
    #pragma unroll
    for (int v = 0; v < 8; v++) outv[v] = f2bfbits(acc[v]);
    bf16x8 store;
    __builtin_memcpy(&store, outv, sizeof(store));
    *(bf16x8*)((short*)Y + (long)node * din + chunk * 64 + sl * 8) = store;
}

// ---------------- tiled GEMM: X_next = tanh(Y @ W + b), optional fused el/er
// 128x128 tile (r11: wider tiles starve block count), BK=64, global_load_lds w16,
// XOR bank swizzle, XCD-aware decode. LDS 32KB; epilogue aliased. (256,4):
// acc = 64 regs on unified file; (256,8) spills (r6).
__global__ __launch_bounds__(256, 4)
void gemm_tiled(const bf16* __restrict__ A, const bf16* __restrict__ WT,
                const float* __restrict__ bias, bf16* __restrict__ C,
                const float* __restrict__ wal, const float* __restrict__ war,
                float* __restrict__ elp, float* __restrict__ erp,
                int M, int K, int N, int ncols, int nrows) {
    __shared__ short smem[16384];   // As=smem[0:8192], Bs=smem[8192:16384]
    short* As = smem;
    short* Bs = smem + 8192;
    int g = blockIdx.x;
    int rowTile = ((g >> 3) / ncols) * 8 + (g & 7);
    int colTile = (g >> 3) % ncols;
    if (rowTile >= nrows) return;
    int row0 = rowTile << 7, col0 = colTile << 7;
    int tid = threadIdx.x;
    int lane = tid & 63, wave = tid >> 6;
    int wr = (wave >> 1) << 6;
    int wc = (wave & 1) << 6;
    int m = lane & 15, quad = lane >> 4;

    f32x4 acc[4][4];
    #pragma unroll
    for (int i = 0; i < 4; i++)
        #pragma unroll
        for (int j = 0; j < 4; j++) acc[i][j] = (f32x4){0.f, 0.f, 0.f, 0.f};

    const short* Ab = (const short*)A;
    const short* Bb = (const short*)WT;
    long ga[4], gb[4];
    #pragma unroll
    for (int n = 0; n < 4; n++) {
        int chunk = n * 256 + tid;
        int row = chunk >> 3;
        int qg = (chunk & 7) ^ (row & 7);
        ga[n] = (long)(row0 + row) * K + qg * 8;
        gb[n] = (long)(col0 + row) * K + qg * 8;
    }

    typedef const __attribute__((address_space(1))) void cgvoid;
    typedef __attribute__((address_space(3))) void lvoid;

    for (int k0 = 0; k0 < K; k0 += 64) {
        __syncthreads();
        #pragma unroll
        for (int n = 0; n < 4; n++)
            __builtin_amdgcn_global_load_lds((cgvoid*)(Ab + ga[n] + k0),
                                             (lvoid*)(As + (n * 256 + tid) * 8), 16, 0, 0);
        #pragma unroll
        for (int n = 0; n < 4; n++)
            __builtin_amdgcn_global_load_lds((cgvoid*)(Bb + gb[n] + k0),
                                             (lvoid*)(Bs + (n * 256 + tid) * 8), 16, 0, 0);
        __syncthreads();
        #pragma unroll
        for (int h = 0; h < 2; h++) {
            bf16x8 af[4], bfr[4];
            #pragma unroll
            for (int s = 0; s < 4; s++) {
                int ra = wr + s * 16 + m;
                int sa = (h * 4 + quad) ^ (ra & 7);
                af[s] = *(const bf16x8*)(As + ra * 64 + sa * 8);
                int rb = wc + s * 16 + m;
                int sb = (h * 4 + quad) ^ (rb & 7);
                bfr[s] = *(const bf16x8*)(Bs + rb * 64 + sb * 8);
            }
            #pragma unroll
            for (int i = 0; i < 4; i++)
                #pragma unroll
                for (int j = 0; j < 4; j++)
                    acc[i][j] = __builtin_amdgcn_mfma_f32_16x16x32_bf16(af[i], bfr[j], acc[i][j], 0, 0, 0);
        }
    }

    // ---- epilogue: bias+tanh (+fused el/er partials), LDS round-trip, b128 stores
    float bb[4], walr[4], warr[4];
    #pragma unroll
    for (int j = 0; j < 4; j++) {
        int col = col0 + wc + j * 16 + m;
        bb[j] = bias[col];
        if (elp) { walr[j] = wal[col]; warr[j] = war[col]; }
    }
    __syncthreads();                      // all waves done reading As/Bs
    short* myep = smem + wave * 1152;     // 16 rows x stride 72 shorts per wave
    #pragma unroll
    for (int i = 0; i < 4; i++) {
        float sl4[4] = {0.f, 0.f, 0.f, 0.f};
        float sr4[4] = {0.f, 0.f, 0.f, 0.f};
        #pragma unroll
        for (int j = 0; j < 4; j++) {
            #pragma unroll
            for (int r = 0; r < 4; r++) {
                float v = tanhf(acc[i][j][r] + bb[j]);
                if (elp) { sl4[r] += v * walr[j]; sr4[r] += v * warr[j]; }
                float vn = __shfl_xor(v, 1);
                if ((m & 1) == 0) {
                    unsigned int pk = (unsigned int)f2bfu(v) | ((unsigned int)f2bfu(vn) << 16);
                    *(unsigned int*)(myep + (quad * 4 + r) * 72 + j * 16 + m) = pk;
                }
            }
        }
        #pragma unroll
        for (int pass = 0; pass < 2; pass++) {
            int lr = pass * 8 + (lane >> 3);
            int lc = (lane & 7) * 8;
            bf16x8 v = *(const bf16x8*)(myep + lr * 72 + lc);
            int row = row0 + wr + i * 16 + lr;
            if (row < M)
                *(bf16x8*)((short*)C + (long)row * N + col0 + wc + lc) = v;
        }
        if (elp) {
            #pragma unroll
            for (int r = 0; r < 4; r++) {
                float s1 = sl4[r], s2 = sr4[r];
                #pragma unroll
                for (int o = 1; o < 16; o <<= 1) {
                    s1 += __shfl_xor(s1, o);
                    s2 += __shfl_xor(s2, o);
                }
                if (m == 0) {
                    int row = row0 + wr + i * 16 + quad * 4 + r;
                    if (row < M) {
                        atomicAdd(&elp[row], s1);
                        atomicAdd(&erp[row], s2);
                    }
                }
            }
        }
    }
}

// ---------------- pool sum: 256 blocks (r15 lesson: narrow head = latency collapse)
__global__ void pool_sum(const bf16* __restrict__ X, const int* __restrict__ order,
                         float* __restrict__ poolsum) {
    int cg = blockIdx.x & 3, rs = blockIdx.x >> 2;
    int c = cg * 256 + threadIdx.x;
    int rows = order[0] + 1;
    float s = 0.f;
    for (int r = rs; r < rows; r += 64) s += b2f(X[(long)r * 1024 + c]);
    atomicAdd(&poolsum[c], s);
}

// ---------------- head ----------------
__global__ void head_logits(const float* __restrict__ poolsum, const float* __restrict__ relW,
                            const float* __restrict__ relB, const int* __restrict__ order,
                            float* __restrict__ logits) {
    int t = blockIdx.x;
    float s = 0.f;
    for (int c = threadIdx.x; c < 1024; c += 256)
        s += poolsum[c] * relW[(long)c * 64 + t];
    __shared__ float sb[256];
    sb[threadIdx.x] = s;
    __syncthreads();
    for (int st = 128; st > 0; st >>= 1) {
        if (threadIdx.x < st) sb[threadIdx.x] += sb[threadIdx.x + st];
        __syncthreads();
    }
    if (threadIdx.x == 0) {
        float rows = (float)(order[0] + 1);
        logits[t] = sb[0] / rows + relB[t];
    }
}

__global__ void head_gather(const float* __restrict__ logits, const int* __restrict__ rel,
                            float* __restrict__ out) {
    __shared__ int nzv[64];
    int t = threadIdx.x;
    if (t == 0) {
        int k = 0;
        for (int i = 0; i < 64; i++)
            if (rel[i] != 0) nzv[k++] = i;
        for (; k < 64; k++) nzv[k] = 0;
    }
    __syncthreads();
    out[t] = logits[nzv[t]];
}

extern "C" void kernel_launch(void* const* d_in, const int* in_sizes, int n_in,
                              void* d_out, int out_size, void* d_ws, size_t ws_size,
                              hipStream_t stream) {
    const float* feat = (const float*)d_in[0];
    const float* W[4]  = {(const float*)d_in[1], (const float*)d_in[5], (const float*)d_in[9],  (const float*)d_in[13]};
    const float* al[4] = {(const float*)d_in[2], (const float*)d_in[6], (const float*)d_in[10], (const float*)d_in[14]};
    const float* ar[4] = {(const float*)d_in[3], (const float*)d_in[7], (const float*)d_in[11], (const float*)d_in[15]};
    const float* bias[4] = {(const float*)d_in[4], (const float*)d_in[8], (const float*)d_in[12], (const float*)d_in[16]};
    const float* relW = (const float*)d_in[17];
    const float* relB = (const float*)d_in[18];
    const int* src = (const int*)d_in[19];
    const int* dst = (const int*)d_in[20];
    const int* rel = (const int*)d_in[21];
    const int* order = (const int*)d_in[22];

    const int dims[5] = {64, 128, 256, 512, 1024};

    char* p = (char*)d_ws;
    auto carve = [&](size_t bytes) {
        void* r = (void*)p;
        p += (bytes + 255) & ~(size_t)255;
        return r;
    };
    bf16* xbuf = (bf16*)carve((size_t)MPAD * 1024 * sizeof(bf16));
    bf16* ybuf = (bf16*)carve((size_t)MPAD * 512 * sizeof(bf16));
    bf16* featb = (bf16*)carve((size_t)MPAD * 64 * sizeof(bf16));
    bf16* wt[4];
    for (int l = 0; l < 4; l++)
        wt[l] = (bf16*)carve((size_t)dims[l] * dims[l + 1] * sizeof(bf16));
    float* walbuf = (float*)carve(4 * 512 * sizeof(float));
    float* warbuf = (float*)carve(4 * 512 * sizeof(float));
    float* elbuf[2];
    elbuf[0] = (float*)carve((size_t)2 * NN * sizeof(float));   // el | er
    elbuf[1] = (float*)carve((size_t)2 * NN * sizeof(float));
    float* alpha = (float*)carve((size_t)NE * sizeof(float));
    int* counts  = (int*)carve((size_t)NN * sizeof(int));
    int* offsets = (int*)carve((size_t)(NN + 1) * sizeof(int));
    int* cursor  = (int*)carve((size_t)NN * sizeof(int));
    int* esrc    = (int*)carve((size_t)NE * sizeof(int));
    int* nodeperm = (int*)carve((size_t)NN * sizeof(int));
    int* blocksums = (int*)carve((size_t)NB * sizeof(int));
    int* hglob   = (int*)carve(256 * sizeof(int));
    int* curg    = (int*)carve(256 * sizeof(int));
    float* poolsum = (float*)carve(1024 * sizeof(float));
    float* logits  = (float*)carve(64 * sizeof(float));

    // ---- 1: setup (wal/war + convert/transpose + counts/h zero) ----
    setup_all<<<960 + 7720, 256, 0, stream>>>(
        feat, W[0], al[0], ar[0], W[1], al[1], ar[1],
        W[2], al[2], ar[2], W[3], al[3], ar[3],
        featb, wt[0], wt[1], wt[2], wt[3], counts, hglob, walbuf, warbuf);

    // ---- 2-5: CSR (wide scan) + degree sort + scatter + layer-1 el/er ----
    hist_kernel<<<(NE + 255) / 256, 256, 0, stream>>>(dst, counts, NE);
    csr_phase1<<<NB, 256, 0, stream>>>(counts, blocksums, hglob);
    csr_phase2<<<NB + 1, 256, 0, stream>>>(counts, blocksums, offsets, cursor, hglob, curg);
    scatter_elr<<<1250 + NB + 5000, 256, 0, stream>>>(src, dst, cursor, esrc,
                                                      counts, curg, nodeperm,
                                                      featb, walbuf, warbuf,
                                                      elbuf[0], elbuf[0] + NN);

    const bf16* x = featb;
    const int nrows = MPAD / 128;     // 157
    const int nrowsPad = 160;
    const int log2c[4] = {0, 1, 2, 3};   // chunks = din/64
    for (int l = 0; l < 4; l++) {
        int K = dims[l], N = dims[l + 1];
        float* elr_rd = elbuf[l & 1];
        float* elr_wr = elbuf[(l + 1) & 1];
        // Last layer: only rows 0..ORD-1 feed the pooling head (order=1023).
        int nsm   = (l < 3) ? NN : ORD;
        int nmax  = (l < 3) ? NN : ORD;
        int nodeBlocks = (nmax + 31) / 32;            // 625 or 32
        const int* aggPerm = (l < 3) ? nodeperm : nullptr;
        edge_softmax_w<<<(nsm + 3) / 4, 256, 0, stream>>>(offsets, esrc, elr_rd,
                                                          elr_rd + NN, alpha, nsm);
        float* zbuf = (l < 3) ? elr_wr : poolsum;
        int zn = (l < 3) ? 2 * NN : 1024;
        aggregate_e<<<nodeBlocks << log2c[l], 256, 0, stream>>>(
            x, alpha, esrc, offsets, aggPerm, zbuf, zn, ybuf, K, log2c[l], nmax);
        int ncols = N >> 7;
        if (l < 3) {
            gemm_tiled<<<nrowsPad * ncols, 256, 0, stream>>>(
                ybuf, wt[l], bias[l], xbuf,
                walbuf + (l + 1) * 512, warbuf + (l + 1) * 512,
                elr_wr, elr_wr + NN,
                NN, K, N, ncols, nrows);
        } else {
            gemm_tiled<<<8 * ncols, 256, 0, stream>>>(
                ybuf, wt[l], bias[l], xbuf,
                nullptr, nullptr, nullptr, nullptr,
                ORD, K, N, ncols, 8);
        }
        x = xbuf;
    }

    // ---- head (poolsum zeroed by L4 aggregate; wide 256-block pool) ----
    pool_sum<<<256, 256, 0, stream>>>(xbuf, order, poolsum);
    head_logits<<<64, 256, 0, stream>>>(poolsum, relW, relB, order, logits);
    head_gather<<<1, 64, 0, stream>>>(logits, rel, (float*)d_out);
}

// Round 18
// 312.879 us; speedup vs baseline: 1.1485x; 1.1485x over previous
//
#include <hip/hip_runtime.h>
#include <hip/hip_bf16.h>

#define NN 20000
#define NE 320000
#define MPAD 20096   // 157 * 128
#define ORD 1024     // rows used by the pooling head (order+1; order fixed = 1023)
#define NB 79        // ceil(NN/256) node blocks for the CSR scan

typedef __hip_bfloat16 bf16;
typedef __attribute__((ext_vector_type(8))) short bf16x8;
typedef __attribute__((ext_vector_type(4))) float f32x4;

static __device__ __forceinline__ float b2f(bf16 x) { return __bfloat162float(x); }
static __device__ __forceinline__ float bfbits2f(short s) {
    unsigned int u = ((unsigned int)(unsigned short)s) << 16;
    float f; __builtin_memcpy(&f, &u, 4); return f;
}
static __device__ __forceinline__ short f2bfbits(float v) {
    bf16 h = __float2bfloat16(v);
    short s; __builtin_memcpy(&s, &h, 2); return s;
}
static __device__ __forceinline__ unsigned short f2bfu(float v) {
    bf16 h = __float2bfloat16(v);
    unsigned short s; __builtin_memcpy(&s, &h, 2); return s;
}

// ---------------- setup: wal/war (blocks 0..959) + convert/transpose/counts/h (960+)
__global__ void setup_all(const float* __restrict__ feat,
                          const float* __restrict__ W1, const float* __restrict__ al1, const float* __restrict__ ar1,
                          const float* __restrict__ W2, const float* __restrict__ al2, const float* __restrict__ ar2,
                          const float* __restrict__ W3, const float* __restrict__ al3, const float* __restrict__ ar3,
                          const float* __restrict__ W4, const float* __restrict__ al4, const float* __restrict__ ar4,
                          bf16* __restrict__ featb, bf16* __restrict__ wt1,
                          bf16* __restrict__ wt2, bf16* __restrict__ wt3,
                          bf16* __restrict__ wt4, int* __restrict__ counts,
                          int* __restrict__ hglob,
                          float* __restrict__ walbuf, float* __restrict__ warbuf) {
    int b = blockIdx.x;
    if (b < 960) {
        const float *W, *al, *ar; int dout, k; float *wal, *war;
        if (b < 64)       { W = W1; al = al1; ar = ar1; dout = 128;  k = b;       wal = walbuf;        war = warbuf; }
        else if (b < 192) { W = W2; al = al2; ar = ar2; dout = 256;  k = b - 64;  wal = walbuf + 512;  war = warbuf + 512; }
        else if (b < 448) { W = W3; al = al3; ar = ar3; dout = 512;  k = b - 192; wal = walbuf + 1024; war = warbuf + 1024; }
        else              { W = W4; al = al4; ar = ar4; dout = 1024; k = b - 448; wal = walbuf + 1536; war = warbuf + 1536; }
        const float* row = W + (long)k * dout;
        float sl = 0.f, sr = 0.f;
        for (int j = threadIdx.x; j < dout; j += 256) {
            float w = row[j];
            sl += w * al[j];
            sr += w * ar[j];
        }
        __shared__ float sbl[256], sbr[256];
        sbl[threadIdx.x] = sl; sbr[threadIdx.x] = sr;
        __syncthreads();
        for (int st = 128; st > 0; st >>= 1) {
            if (threadIdx.x < st) {
                sbl[threadIdx.x] += sbl[threadIdx.x + st];
                sbr[threadIdx.x] += sbr[threadIdx.x + st];
            }
            __syncthreads();
        }
        if (threadIdx.x == 0) { wal[k] = sbl[0]; war[k] = sbr[0]; }
        return;
    }
    int i = (b - 960) * 256 + threadIdx.x;
    if (i < NN) counts[i] = 0;
    if (i < 256) hglob[i] = 0;
    if (i < 1280000) { featb[i] = __float2bfloat16(feat[i]); return; }
    i -= 1280000;
    if (i < 8192)  { int r = i >> 7,  c = i & 127;  wt1[c * 64 + r]  = __float2bfloat16(W1[i]); return; }
    i -= 8192;
    if (i < 32768) { int r = i >> 8,  c = i & 255;  wt2[c * 128 + r] = __float2bfloat16(W2[i]); return; }
    i -= 32768;
    if (i < 131072){ int r = i >> 9,  c = i & 511;  wt3[c * 256 + r] = __float2bfloat16(W3[i]); return; }
    i -= 131072;
    if (i < 524288){ int r = i >> 10, c = i & 1023; wt4[c * 512 + r] = __float2bfloat16(W4[i]); return; }
}

// ---------------- CSR hist ----------------
__global__ void hist_kernel(const int* __restrict__ dst, int* __restrict__ counts, int n) {
    int i = blockIdx.x * blockDim.x + threadIdx.x;
    if (i < n) atomicAdd(&counts[dst[i]], 1);
}

// ---------------- CSR phase1 (WIDE): per-block count sums + degree histogram
__global__ void csr_phase1(const int* __restrict__ counts, int* __restrict__ blocksums,
                           int* __restrict__ hglob) {
    __shared__ int sb[256];
    __shared__ int hh[256];
    int tid = threadIdx.x;
    hh[tid] = 0;
    int i = blockIdx.x * 256 + tid;
    int c = (i < NN) ? counts[i] : 0;
    sb[tid] = c;
    __syncthreads();
    for (int st = 128; st > 0; st >>= 1) {
        if (tid < st) sb[tid] += sb[tid + st];
        __syncthreads();
    }
    if (tid == 0) blocksums[blockIdx.x] = sb[0];
    if (i < NN) {
        int d = c > 255 ? 255 : c;
        atomicAdd(&hh[d], 1);
    }
    __syncthreads();
    if (hh[tid] > 0) atomicAdd(&hglob[tid], hh[tid]);
}

// ---------------- CSR phase2 (WIDE): offsets/cursor + bucket cursors ----------------
__global__ void csr_phase2(const int* __restrict__ counts, const int* __restrict__ blocksums,
                           int* __restrict__ offsets, int* __restrict__ cursor,
                           const int* __restrict__ hglob, int* __restrict__ curg) {
    int tid = threadIdx.x;
    if (blockIdx.x == NB) {
        __shared__ int hs[256];
        int orig = hglob[tid];
        hs[tid] = orig;
        __syncthreads();
        for (int st = 1; st < 256; st <<= 1) {
            int u = (tid >= st) ? hs[tid - st] : 0;
            __syncthreads();
            hs[tid] += u;
            __syncthreads();
        }
        curg[tid] = hs[tid] - orig;
        return;
    }
    __shared__ int bs[256];
    bs[tid] = (tid < NB) ? blocksums[tid] : 0;
    __syncthreads();
    for (int st = 1; st < 256; st <<= 1) {
        int u = (tid >= st) ? bs[tid - st] : 0;
        __syncthreads();
        bs[tid] += u;
        __syncthreads();
    }
    int base = (blockIdx.x == 0) ? 0 : bs[blockIdx.x - 1];
    __shared__ int sc[256];
    int i = blockIdx.x * 256 + tid;
    int c = (i < NN) ? counts[i] : 0;
    sc[tid] = c;
    __syncthreads();
    for (int st = 1; st < 256; st <<= 1) {
        int u = (tid >= st) ? sc[tid - st] : 0;
        __syncthreads();
        sc[tid] += u;
        __syncthreads();
    }
    int excl = base + sc[tid] - c;
    if (i < NN) { offsets[i] = excl; cursor[i] = excl; }
    if (i == NN - 1) offsets[NN] = excl + c;
}

// ---------------- scatter (0..1249) + perm scatter (1250..1328) + L1 el/er (1329+)
// Perm: two-level reservation (r17 lesson: per-node global atomics on ~17 hot
// degree buckets = ~1200-deep RMW chains, +22us). LDS rank + ONE global
// atomicAdd per (block,bucket). Within-bucket order nondeterministic — fine (r4).
__global__ void scatter_elr(const int* __restrict__ src, const int* __restrict__ dst,
                            int* __restrict__ cursor, int* __restrict__ esrc,
                            const int* __restrict__ counts, int* __restrict__ curg,
                            int* __restrict__ nodeperm,
                            const bf16* __restrict__ X, const float* __restrict__ wal,
                            const float* __restrict__ war, float* __restrict__ el,
                            float* __restrict__ er) {
    int b = blockIdx.x;
    if (b < 1250) {
        int i = b * 256 + threadIdx.x;   // 1250*256 = 320000 = NE exactly
        int p = atomicAdd(&cursor[dst[i]], 1);
        esrc[p] = src[i];
        return;
    }
    if (b < 1250 + NB) {
        __shared__ int hh[256];
        __shared__ int basep[256];
        int tid = threadIdx.x;
        hh[tid] = 0;
        __syncthreads();
        int i = (b - 1250) * 256 + tid;
        int d = 0, rank = 0;
        bool valid = (i < NN);
        if (valid) {
            d = counts[i]; if (d > 255) d = 255;
            rank = atomicAdd(&hh[d], 1);      // LDS rank within (block,bucket)
        }
        __syncthreads();
        if (hh[tid] > 0) basep[tid] = atomicAdd(&curg[tid], hh[tid]);  // 1 global/bucket
        __syncthreads();
        if (valid) nodeperm[basep[d] + rank] = i;
        return;
    }
    int idx = (b - 1250 - NB) * 256 + threadIdx.x;
    int node = idx >> 6;
    int lane = threadIdx.x & 63;
    if (node >= NN) return;
    float x = bfbits2f(*((const short*)X + (long)node * 64 + lane));
    float sl = x * wal[lane];
    float sr = x * war[lane];
    #pragma unroll
    for (int o = 32; o > 0; o >>= 1) {
        sl += __shfl_down(sl, o);
        sr += __shfl_down(sr, o);
    }
    if (lane == 0) { el[node] = sl; er[node] = sr; }
}

// ---------------- edge softmax: WAVE per node, lanes parallel over edges.
// Each alpha computed exactly ONCE (r12 lesson). Natural node order (r8 lesson).
__global__ void edge_softmax_w(const int* __restrict__ off, const int* __restrict__ esrc,
                               const float* __restrict__ el, const float* __restrict__ er,
                               float* __restrict__ alpha, int n) {
    int node = blockIdx.x * 4 + (threadIdx.x >> 6);
    if (node >= n) return;
    int lane = threadIdx.x & 63;
    int s = off[node], e = off[node + 1];
    int deg = e - s;
    if (deg <= 0) return;
    float erd = er[node];
    if (deg <= 64) {
        float v = -1e30f;
        if (lane < deg) {
            float t = el[esrc[s + lane]] + erd;
            v = t >= 0.f ? t : 0.2f * t;
        }
        float mx = v;
        #pragma unroll
        for (int o = 32; o > 0; o >>= 1) mx = fmaxf(mx, __shfl_xor(mx, o));
        float x = (lane < deg) ? __expf(v - mx) : 0.f;
        float ssum = x;
        #pragma unroll
        for (int o = 32; o > 0; o >>= 1) ssum += __shfl_xor(ssum, o);
        if (lane < deg) alpha[s + lane] = x / ssum;
    } else if (deg <= 256) {
        float v[4];
        float mx = -1e30f;
        #pragma unroll
        for (int r = 0; r < 4; r++) {
            v[r] = -1e30f;
            if (r * 64 + lane < deg) {
                float t = el[esrc[s + r * 64 + lane]] + erd;
                v[r] = t >= 0.f ? t : 0.2f * t;
            }
            mx = fmaxf(mx, v[r]);
        }
        #pragma unroll
        for (int o = 32; o > 0; o >>= 1) mx = fmaxf(mx, __shfl_xor(mx, o));
        float ssum = 0.f;
        #pragma unroll
        for (int r = 0; r < 4; r++) {
            v[r] = (r * 64 + lane < deg) ? __expf(v[r] - mx) : 0.f;
            ssum += v[r];
        }
        #pragma unroll
        for (int o = 32; o > 0; o >>= 1) ssum += __shfl_xor(ssum, o);
        float inv = 1.f / ssum;
        #pragma unroll
        for (int r = 0; r < 4; r++)
            if (r * 64 + lane < deg) alpha[s + r * 64 + lane] = v[r] * inv;
    } else if (lane == 0) {
        float mx = -1e30f;
        for (int j = s; j < e; j++) {
            float t = el[esrc[j]] + erd;
            t = t >= 0.f ? t : 0.2f * t;
            alpha[j] = t;
            mx = fmaxf(mx, t);
        }
        float ssum = 0.f;
        for (int j = s; j < e; j++) { float x = __expf(alpha[j] - mx); alpha[j] = x; ssum += x; }
        float inv = 1.f / ssum;
        for (int j = s; j < e; j++) alpha[j] *= inv;
    }
}

// ---------------- Y = A @ X, 64-ch chunks: eighth-wave (8 lanes x 16B) per node.
// chunk = blockIdx LSBs pins each 2.5MB X-slice to one XCD L2 (r8).
// 8-way edge unroll = 8x MLP on the ~200cy L2 chain (r13).
// perm==nullptr -> natural node order (1024-node last layer).
// Also zeros zbuf[0:zn) — producer-side zeroing.
__global__ void aggregate_e(const bf16* __restrict__ X, const float* __restrict__ alpha,
                            const int* __restrict__ esrc, const int* __restrict__ off,
                            const int* __restrict__ perm, float* __restrict__ zbuf, int zn,
                            bf16* __restrict__ Y, int din, int log2chunks, int nmax) {
    {
        int z = blockIdx.x * 256 + threadIdx.x;
        if (z < zn) zbuf[z] = 0.f;
    }
    int chunk = blockIdx.x & ((1 << log2chunks) - 1);
    int nb = blockIdx.x >> log2chunks;
    int sub = threadIdx.x >> 3, sl = threadIdx.x & 7;
    int slot = nb * 32 + sub;
    if (slot >= nmax) return;
    int node = perm ? perm[slot] : slot;
    const short* xb = (const short*)X + chunk * 64 + sl * 8;
    float acc[8] = {0.f,0.f,0.f,0.f,0.f,0.f,0.f,0.f};
    int s = off[node], e = off[node + 1];
    int j = s;
    for (; j + 8 <= e; j += 8) {
        float a[8]; int r[8]; bf16x8 w[8];
        #pragma unroll
        for (int q = 0; q < 8; q++) { a[q] = alpha[j + q]; r[q] = esrc[j + q]; }
        #pragma unroll
        for (int q = 0; q < 8; q++) w[q] = *(const bf16x8*)(xb + (long)r[q] * din);
        #pragma unroll
        for (int q = 0; q < 8; q++)
            #pragma unroll
            for (int v = 0; v < 8; v++) acc[v] += a[q] * bfbits2f(w[q][v]);
    }
    for (; j + 4 <= e; j += 4) {
        float a0 = alpha[j],     a1 = alpha[j + 1];
        float a2 = alpha[j + 2], a3 = alpha[j + 3];
        int r0 = esrc[j],     r1 = esrc[j + 1];
        int r2 = esrc[j + 2], r3 = esrc[j + 3];
        bf16x8 w0 = *(const bf16x8*)(xb + (long)r0 * din);
        bf16x8 w1 = *(const bf16x8*)(xb + (long)r1 * din);
        bf16x8 w2 = *(const bf16x8*)(xb + (long)r2 * din);
        bf16x8 w3 = *(const bf16x8*)(xb + (long)r3 * din);
        #pragma unroll
        for (int v = 0; v < 8; v++) acc[v] += a0 * bfbits2f(w0[v]);
        #pragma unroll
        for (int v = 0; v < 8; v++) acc[v] += a1 * bfbits2f(w1[v]);
        #pragma unroll
        for (int v = 0; v < 8; v++) acc[v] += a2 * bfbits2f(w2[v]);
        #pragma unroll
        for (int v = 0; v < 8; v++) acc[v] += a3 * bfbits2f(w3[v]);
    }
    for (; j < e; j++) {
        float a = alpha[j];
        bf16x8 w = *(const bf16x8*)(xb + (long)esrc[j] * din);
        #pragma unroll
        for (int v = 0; v < 8; v++) acc[v] += a * bfbits2f(w[v]);
    }
    short outv[8];
    #pragma unroll
    for (int v = 0; v < 8; v++) outv[v] = f2bfbits(acc[v]);
    bf16x8 store;
    __builtin_memcpy(&store, outv, sizeof(store));
    *(bf16x8*)((short*)Y + (long)node * din + chunk * 64 + sl * 8) = store;
}

// ---------------- tiled GEMM: X_next = tanh(Y @ W + b), optional fused el/er
// 128x128 tile (r11: wider tiles starve block count), BK=64, global_load_lds w16,
// XOR bank swizzle, XCD-aware decode. LDS 32KB; epilogue aliased. (256,4):
// acc = 64 regs on unified file; (256,8) spills (r6).
__global__ __launch_bounds__(256, 4)
void gemm_tiled(const bf16* __restrict__ A, const bf16* __restrict__ WT,
                const float* __restrict__ bias, bf16* __restrict__ C,
                const float* __restrict__ wal, const float* __restrict__ war,
                float* __restrict__ elp, float* __restrict__ erp,
                int M, int K, int N, int ncols, int nrows) {
    __shared__ short smem[16384];   // As=smem[0:8192], Bs=smem[8192:16384]
    short* As = smem;
    short* Bs = smem + 8192;
    int g = blockIdx.x;
    int rowTile = ((g >> 3) / ncols) * 8 + (g & 7);
    int colTile = (g >> 3) % ncols;
    if (rowTile >= nrows) return;
    int row0 = rowTile << 7, col0 = colTile << 7;
    int tid = threadIdx.x;
    int lane = tid & 63, wave = tid >> 6;
    int wr = (wave >> 1) << 6;
    int wc = (wave & 1) << 6;
    int m = lane & 15, quad = lane >> 4;

    f32x4 acc[4][4];
    #pragma unroll
    for (int i = 0; i < 4; i++)
        #pragma unroll
        for (int j = 0; j < 4; j++) acc[i][j] = (f32x4){0.f, 0.f, 0.f, 0.f};

    const short* Ab = (const short*)A;
    const short* Bb = (const short*)WT;
    long ga[4], gb[4];
    #pragma unroll
    for (int n = 0; n < 4; n++) {
        int chunk = n * 256 + tid;
        int row = chunk >> 3;
        int qg = (chunk & 7) ^ (row & 7);
        ga[n] = (long)(row0 + row) * K + qg * 8;
        gb[n] = (long)(col0 + row) * K + qg * 8;
    }

    typedef const __attribute__((address_space(1))) void cgvoid;
    typedef __attribute__((address_space(3))) void lvoid;

    for (int k0 = 0; k0 < K; k0 += 64) {
        __syncthreads();
        #pragma unroll
        for (int n = 0; n < 4; n++)
            __builtin_amdgcn_global_load_lds((cgvoid*)(Ab + ga[n] + k0),
                                             (lvoid*)(As + (n * 256 + tid) * 8), 16, 0, 0);
        #pragma unroll
        for (int n = 0; n < 4; n++)
            __builtin_amdgcn_global_load_lds((cgvoid*)(Bb + gb[n] + k0),
                                             (lvoid*)(Bs + (n * 256 + tid) * 8), 16, 0, 0);
        __syncthreads();
        #pragma unroll
        for (int h = 0; h < 2; h++) {
            bf16x8 af[4], bfr[4];
            #pragma unroll
            for (int s = 0; s < 4; s++) {
                int ra = wr + s * 16 + m;
                int sa = (h * 4 + quad) ^ (ra & 7);
                af[s] = *(const bf16x8*)(As + ra * 64 + sa * 8);
                int rb = wc + s * 16 + m;
                int sb = (h * 4 + quad) ^ (rb & 7);
                bfr[s] = *(const bf16x8*)(Bs + rb * 64 + sb * 8);
            }
            #pragma unroll
            for (int i = 0; i < 4; i++)
                #pragma unroll
                for (int j = 0; j < 4; j++)
                    acc[i][j] = __builtin_amdgcn_mfma_f32_16x16x32_bf16(af[i], bfr[j], acc[i][j], 0, 0, 0);
        }
    }

    // ---- epilogue: bias+tanh (+fused el/er partials), LDS round-trip, b128 stores
    float bb[4], walr[4], warr[4];
    #pragma unroll
    for (int j = 0; j < 4; j++) {
        int col = col0 + wc + j * 16 + m;
        bb[j] = bias[col];
        if (elp) { walr[j] = wal[col]; warr[j] = war[col]; }
    }
    __syncthreads();                      // all waves done reading As/Bs
    short* myep = smem + wave * 1152;     // 16 rows x stride 72 shorts per wave
    #pragma unroll
    for (int i = 0; i < 4; i++) {
        float sl4[4] = {0.f, 0.f, 0.f, 0.f};
        float sr4[4] = {0.f, 0.f, 0.f, 0.f};
        #pragma unroll
        for (int j = 0; j < 4; j++) {
            #pragma unroll
            for (int r = 0; r < 4; r++) {
                float v = tanhf(acc[i][j][r] + bb[j]);
                if (elp) { sl4[r] += v * walr[j]; sr4[r] += v * warr[j]; }
                float vn = __shfl_xor(v, 1);
                if ((m & 1) == 0) {
                    unsigned int pk = (unsigned int)f2bfu(v) | ((unsigned int)f2bfu(vn) << 16);
                    *(unsigned int*)(myep + (quad * 4 + r) * 72 + j * 16 + m) = pk;
                }
            }
        }
        #pragma unroll
        for (int pass = 0; pass < 2; pass++) {
            int lr = pass * 8 + (lane >> 3);
            int lc = (lane & 7) * 8;
            bf16x8 v = *(const bf16x8*)(myep + lr * 72 + lc);
            int row = row0 + wr + i * 16 + lr;
            if (row < M)
                *(bf16x8*)((short*)C + (long)row * N + col0 + wc + lc) = v;
        }
        if (elp) {
            #pragma unroll
            for (int r = 0; r < 4; r++) {
                float s1 = sl4[r], s2 = sr4[r];
                #pragma unroll
                for (int o = 1; o < 16; o <<= 1) {
                    s1 += __shfl_xor(s1, o);
                    s2 += __shfl_xor(s2, o);
                }
                if (m == 0) {
                    int row = row0 + wr + i * 16 + quad * 4 + r;
                    if (row < M) {
                        atomicAdd(&elp[row], s1);
                        atomicAdd(&erp[row], s2);
                    }
                }
            }
        }
    }
}

// ---------------- pool sum: 256 blocks (r15 lesson: narrow head = latency collapse)
__global__ void pool_sum(const bf16* __restrict__ X, const int* __restrict__ order,
                         float* __restrict__ poolsum) {
    int cg = blockIdx.x & 3, rs = blockIdx.x >> 2;
    int c = cg * 256 + threadIdx.x;
    int rows = order[0] + 1;
    float s = 0.f;
    for (int r = rs; r < rows; r += 64) s += b2f(X[(long)r * 1024 + c]);
    atomicAdd(&poolsum[c], s);
}

// ---------------- head ----------------
__global__ void head_logits(const float* __restrict__ poolsum, const float* __restrict__ relW,
                            const float* __restrict__ relB, const int* __restrict__ order,
                            float* __restrict__ logits) {
    int t = blockIdx.x;
    float s = 0.f;
    for (int c = threadIdx.x; c < 1024; c += 256)
        s += poolsum[c] * relW[(long)c * 64 + t];
    __shared__ float sb[256];
    sb[threadIdx.x] = s;
    __syncthreads();
    for (int st = 128; st > 0; st >>= 1) {
        if (threadIdx.x < st) sb[threadIdx.x] += sb[threadIdx.x + st];
        __syncthreads();
    }
    if (threadIdx.x == 0) {
        float rows = (float)(order[0] + 1);
        logits[t] = sb[0] / rows + relB[t];
    }
}

__global__ void head_gather(const float* __restrict__ logits, const int* __restrict__ rel,
                            float* __restrict__ out) {
    __shared__ int nzv[64];
    int t = threadIdx.x;
    if (t == 0) {
        int k = 0;
        for (int i = 0; i < 64; i++)
            if (rel[i] != 0) nzv[k++] = i;
        for (; k < 64; k++) nzv[k] = 0;
    }
    __syncthreads();
    out[t] = logits[nzv[t]];
}

extern "C" void kernel_launch(void* const* d_in, const int* in_sizes, int n_in,
                              void* d_out, int out_size, void* d_ws, size_t ws_size,
                              hipStream_t stream) {
    const float* feat = (const float*)d_in[0];
    const float* W[4]  = {(const float*)d_in[1], (const float*)d_in[5], (const float*)d_in[9],  (const float*)d_in[13]};
    const float* al[4] = {(const float*)d_in[2], (const float*)d_in[6], (const float*)d_in[10], (const float*)d_in[14]};
    const float* ar[4] = {(const float*)d_in[3], (const float*)d_in[7], (const float*)d_in[11], (const float*)d_in[15]};
    const float* bias[4] = {(const float*)d_in[4], (const float*)d_in[8], (const float*)d_in[12], (const float*)d_in[16]};
    const float* relW = (const float*)d_in[17];
    const float* relB = (const float*)d_in[18];
    const int* src = (const int*)d_in[19];
    const int* dst = (const int*)d_in[20];
    const int* rel = (const int*)d_in[21];
    const int* order = (const int*)d_in[22];

    const int dims[5] = {64, 128, 256, 512, 1024};

    char* p = (char*)d_ws;
    auto carve = [&](size_t bytes) {
        void* r = (void*)p;
        p += (bytes + 255) & ~(size_t)255;
        return r;
    };
    bf16* xbuf = (bf16*)carve((size_t)MPAD * 1024 * sizeof(bf16));
    bf16* ybuf = (bf16*)carve((size_t)MPAD * 512 * sizeof(bf16));
    bf16* featb = (bf16*)carve((size_t)MPAD * 64 * sizeof(bf16));
    bf16* wt[4];
    for (int l = 0; l < 4; l++)
        wt[l] = (bf16*)carve((size_t)dims[l] * dims[l + 1] * sizeof(bf16));
    float* walbuf = (float*)carve(4 * 512 * sizeof(float));
    float* warbuf = (float*)carve(4 * 512 * sizeof(float));
    float* elbuf[2];
    elbuf[0] = (float*)carve((size_t)2 * NN * sizeof(float));   // el | er
    elbuf[1] = (float*)carve((size_t)2 * NN * sizeof(float));
    float* alpha = (float*)carve((size_t)NE * sizeof(float));
    int* counts  = (int*)carve((size_t)NN * sizeof(int));
    int* offsets = (int*)carve((size_t)(NN + 1) * sizeof(int));
    int* cursor  = (int*)carve((size_t)NN * sizeof(int));
    int* esrc    = (int*)carve((size_t)NE * sizeof(int));
    int* nodeperm = (int*)carve((size_t)NN * sizeof(int));
    int* blocksums = (int*)carve((size_t)NB * sizeof(int));
    int* hglob   = (int*)carve(256 * sizeof(int));
    int* curg    = (int*)carve(256 * sizeof(int));
    float* poolsum = (float*)carve(1024 * sizeof(float));
    float* logits  = (float*)carve(64 * sizeof(float));

    // ---- 1: setup (wal/war + convert/transpose + counts/h zero) ----
    setup_all<<<960 + 7720, 256, 0, stream>>>(
        feat, W[0], al[0], ar[0], W[1], al[1], ar[1],
        W[2], al[2], ar[2], W[3], al[3], ar[3],
        featb, wt[0], wt[1], wt[2], wt[3], counts, hglob, walbuf, warbuf);

    // ---- 2-5: CSR (wide scan) + degree sort + scatter + layer-1 el/er ----
    hist_kernel<<<(NE + 255) / 256, 256, 0, stream>>>(dst, counts, NE);
    csr_phase1<<<NB, 256, 0, stream>>>(counts, blocksums, hglob);
    csr_phase2<<<NB + 1, 256, 0, stream>>>(counts, blocksums, offsets, cursor, hglob, curg);
    scatter_elr<<<1250 + NB + 5000, 256, 0, stream>>>(src, dst, cursor, esrc,
                                                      counts, curg, nodeperm,
                                                      featb, walbuf, warbuf,
                                                      elbuf[0], elbuf[0] + NN);

    const bf16* x = featb;
    const int nrows = MPAD / 128;     // 157
    const int nrowsPad = 160;
    const int log2c[4] = {0, 1, 2, 3};   // chunks = din/64
    for (int l = 0; l < 4; l++) {
        int K = dims[l], N = dims[l + 1];
        float* elr_rd = elbuf[l & 1];
        float* elr_wr = elbuf[(l + 1) & 1];
        // Last layer: only rows 0..ORD-1 feed the pooling head (order=1023).
        int nsm   = (l < 3) ? NN : ORD;
        int nmax  = (l < 3) ? NN : ORD;
        int nodeBlocks = (nmax + 31) / 32;            // 625 or 32
        const int* aggPerm = (l < 3) ? nodeperm : nullptr;
        edge_softmax_w<<<(nsm + 3) / 4, 256, 0, stream>>>(offsets, esrc, elr_rd,
                                                          elr_rd + NN, alpha, nsm);
        float* zbuf = (l < 3) ? elr_wr : poolsum;
        int zn = (l < 3) ? 2 * NN : 1024;
        aggregate_e<<<nodeBlocks << log2c[l], 256, 0, stream>>>(
            x, alpha, esrc, offsets, aggPerm, zbuf, zn, ybuf, K, log2c[l], nmax);
        int ncols = N >> 7;
        if (l < 3) {
            gemm_tiled<<<nrowsPad * ncols, 256, 0, stream>>>(
                ybuf, wt[l], bias[l], xbuf,
                walbuf + (l + 1) * 512, warbuf + (l + 1) * 512,
                elr_wr, elr_wr + NN,
                NN, K, N, ncols, nrows);
        } else {
            gemm_tiled<<<8 * ncols, 256, 0, stream>>>(
                ybuf, wt[l], bias[l], xbuf,
                nullptr, nullptr, nullptr, nullptr,
                ORD, K, N, ncols, 8);
        }
        x = xbuf;
    }

    // ---- head (poolsum zeroed by L4 aggregate; wide 256-block pool) ----
    pool_sum<<<256, 256, 0, stream>>>(xbuf, order, poolsum);
    head_logits<<<64, 256, 0, stream>>>(poolsum, relW, relB, order, logits);
    head_gather<<<1, 64, 0, stream>>>(logits, rel, (float*)d_out);
}

// Round 19
// 302.841 us; speedup vs baseline: 1.1866x; 1.0331x over previous
//
#include <hip/hip_runtime.h>
#include <hip/hip_bf16.h>

#define NN 20000
#define NE 320000
#define MPAD 20096   // 157 * 128
#define ORD 1024     // rows used by the pooling head (order+1; order fixed = 1023)
#define NB 79        // ceil(NN/256) node blocks for the CSR scan

typedef __hip_bfloat16 bf16;
typedef __attribute__((ext_vector_type(8))) short bf16x8;
typedef __attribute__((ext_vector_type(4))) float f32x4;

static __device__ __forceinline__ float b2f(bf16 x) { return __bfloat162float(x); }
static __device__ __forceinline__ float bfbits2f(short s) {
    unsigned int u = ((unsigned int)(unsigned short)s) << 16;
    float f; __builtin_memcpy(&f, &u, 4); return f;
}
static __device__ __forceinline__ short f2bfbits(float v) {
    bf16 h = __float2bfloat16(v);
    short s; __builtin_memcpy(&s, &h, 2); return s;
}
static __device__ __forceinline__ unsigned short f2bfu(float v) {
    bf16 h = __float2bfloat16(v);
    unsigned short s; __builtin_memcpy(&s, &h, 2); return s;
}

// ---------------- setup: wal/war (blocks 0..959) + convert/transpose/counts/h (960+)
__global__ void setup_all(const float* __restrict__ feat,
                          const float* __restrict__ W1, const float* __restrict__ al1, const float* __restrict__ ar1,
                          const float* __restrict__ W2, const float* __restrict__ al2, const float* __restrict__ ar2,
                          const float* __restrict__ W3, const float* __restrict__ al3, const float* __restrict__ ar3,
                          const float* __restrict__ W4, const float* __restrict__ al4, const float* __restrict__ ar4,
                          bf16* __restrict__ featb, bf16* __restrict__ wt1,
                          bf16* __restrict__ wt2, bf16* __restrict__ wt3,
                          bf16* __restrict__ wt4, int* __restrict__ counts,
                          int* __restrict__ hglob,
                          float* __restrict__ walbuf, float* __restrict__ warbuf) {
    int b = blockIdx.x;
    if (b < 960) {
        const float *W, *al, *ar; int dout, k; float *wal, *war;
        if (b < 64)       { W = W1; al = al1; ar = ar1; dout = 128;  k = b;       wal = walbuf;        war = warbuf; }
        else if (b < 192) { W = W2; al = al2; ar = ar2; dout = 256;  k = b - 64;  wal = walbuf + 512;  war = warbuf + 512; }
        else if (b < 448) { W = W3; al = al3; ar = ar3; dout = 512;  k = b - 192; wal = walbuf + 1024; war = warbuf + 1024; }
        else              { W = W4; al = al4; ar = ar4; dout = 1024; k = b - 448; wal = walbuf + 1536; war = warbuf + 1536; }
        const float* row = W + (long)k * dout;
        float sl = 0.f, sr = 0.f;
        for (int j = threadIdx.x; j < dout; j += 256) {
            float w = row[j];
            sl += w * al[j];
            sr += w * ar[j];
        }
        __shared__ float sbl[256], sbr[256];
        sbl[threadIdx.x] = sl; sbr[threadIdx.x] = sr;
        __syncthreads();
        for (int st = 128; st > 0; st >>= 1) {
            if (threadIdx.x < st) {
                sbl[threadIdx.x] += sbl[threadIdx.x + st];
                sbr[threadIdx.x] += sbr[threadIdx.x + st];
            }
            __syncthreads();
        }
        if (threadIdx.x == 0) { wal[k] = sbl[0]; war[k] = sbr[0]; }
        return;
    }
    int i = (b - 960) * 256 + threadIdx.x;
    if (i < NN) counts[i] = 0;
    if (i < 256) hglob[i] = 0;
    if (i < 1280000) { featb[i] = __float2bfloat16(feat[i]); return; }
    i -= 1280000;
    if (i < 8192)  { int r = i >> 7,  c = i & 127;  wt1[c * 64 + r]  = __float2bfloat16(W1[i]); return; }
    i -= 8192;
    if (i < 32768) { int r = i >> 8,  c = i & 255;  wt2[c * 128 + r] = __float2bfloat16(W2[i]); return; }
    i -= 32768;
    if (i < 131072){ int r = i >> 9,  c = i & 511;  wt3[c * 256 + r] = __float2bfloat16(W3[i]); return; }
    i -= 131072;
    if (i < 524288){ int r = i >> 10, c = i & 1023; wt4[c * 512 + r] = __float2bfloat16(W4[i]); return; }
}

// ---------------- CSR hist ----------------
__global__ void hist_kernel(const int* __restrict__ dst, int* __restrict__ counts, int n) {
    int i = blockIdx.x * blockDim.x + threadIdx.x;
    if (i < n) atomicAdd(&counts[dst[i]], 1);
}

// ---------------- CSR phase1 (WIDE): per-block count sums + degree histogram
__global__ void csr_phase1(const int* __restrict__ counts, int* __restrict__ blocksums,
                           int* __restrict__ hglob) {
    __shared__ int sb[256];
    __shared__ int hh[256];
    int tid = threadIdx.x;
    hh[tid] = 0;
    int i = blockIdx.x * 256 + tid;
    int c = (i < NN) ? counts[i] : 0;
    sb[tid] = c;
    __syncthreads();
    for (int st = 128; st > 0; st >>= 1) {
        if (tid < st) sb[tid] += sb[tid + st];
        __syncthreads();
    }
    if (tid == 0) blocksums[blockIdx.x] = sb[0];
    if (i < NN) {
        int d = c > 255 ? 255 : c;
        atomicAdd(&hh[d], 1);
    }
    __syncthreads();
    if (hh[tid] > 0) atomicAdd(&hglob[tid], hh[tid]);
}

// ---------------- CSR phase2 (WIDE): offsets/cursor + bucket cursors ----------------
__global__ void csr_phase2(const int* __restrict__ counts, const int* __restrict__ blocksums,
                           int* __restrict__ offsets, int* __restrict__ cursor,
                           const int* __restrict__ hglob, int* __restrict__ curg) {
    int tid = threadIdx.x;
    if (blockIdx.x == NB) {
        __shared__ int hs[256];
        int orig = hglob[tid];
        hs[tid] = orig;
        __syncthreads();
        for (int st = 1; st < 256; st <<= 1) {
            int u = (tid >= st) ? hs[tid - st] : 0;
            __syncthreads();
            hs[tid] += u;
            __syncthreads();
        }
        curg[tid] = hs[tid] - orig;
        return;
    }
    __shared__ int bs[256];
    bs[tid] = (tid < NB) ? blocksums[tid] : 0;
    __syncthreads();
    for (int st = 1; st < 256; st <<= 1) {
        int u = (tid >= st) ? bs[tid - st] : 0;
        __syncthreads();
        bs[tid] += u;
        __syncthreads();
    }
    int base = (blockIdx.x == 0) ? 0 : bs[blockIdx.x - 1];
    __shared__ int sc[256];
    int i = blockIdx.x * 256 + tid;
    int c = (i < NN) ? counts[i] : 0;
    sc[tid] = c;
    __syncthreads();
    for (int st = 1; st < 256; st <<= 1) {
        int u = (tid >= st) ? sc[tid - st] : 0;
        __syncthreads();
        sc[tid] += u;
        __syncthreads();
    }
    int excl = base + sc[tid] - c;
    if (i < NN) { offsets[i] = excl; cursor[i] = excl; }
    if (i == NN - 1) offsets[NN] = excl + c;
}

// ---------------- scatter (0..1249) + perm scatter (1250..1328) + L1 el/er (1329+)
// Perm: two-level reservation (r17 lesson: per-node global atomics on ~17 hot
// buckets = deep RMW chains). LDS rank + ONE global atomicAdd per (block,bucket).
__global__ void scatter_elr(const int* __restrict__ src, const int* __restrict__ dst,
                            int* __restrict__ cursor, int* __restrict__ esrc,
                            const int* __restrict__ counts, int* __restrict__ curg,
                            int* __restrict__ nodeperm,
                            const bf16* __restrict__ X, const float* __restrict__ wal,
                            const float* __restrict__ war, float* __restrict__ el,
                            float* __restrict__ er) {
    int b = blockIdx.x;
    if (b < 1250) {
        int i = b * 256 + threadIdx.x;   // 1250*256 = 320000 = NE exactly
        int p = atomicAdd(&cursor[dst[i]], 1);
        esrc[p] = src[i];
        return;
    }
    if (b < 1250 + NB) {
        __shared__ int hh[256];
        __shared__ int basep[256];
        int tid = threadIdx.x;
        hh[tid] = 0;
        __syncthreads();
        int i = (b - 1250) * 256 + tid;
        int d = 0, rank = 0;
        bool valid = (i < NN);
        if (valid) {
            d = counts[i]; if (d > 255) d = 255;
            rank = atomicAdd(&hh[d], 1);      // LDS rank within (block,bucket)
        }
        __syncthreads();
        if (hh[tid] > 0) basep[tid] = atomicAdd(&curg[tid], hh[tid]);  // 1 global/bucket
        __syncthreads();
        if (valid) nodeperm[basep[d] + rank] = i;
        return;
    }
    int idx = (b - 1250 - NB) * 256 + threadIdx.x;
    int node = idx >> 6;
    int lane = threadIdx.x & 63;
    if (node >= NN) return;
    float x = bfbits2f(*((const short*)X + (long)node * 64 + lane));
    float sl = x * wal[lane];
    float sr = x * war[lane];
    #pragma unroll
    for (int o = 32; o > 0; o >>= 1) {
        sl += __shfl_down(sl, o);
        sr += __shfl_down(sr, o);
    }
    if (lane == 0) { el[node] = sl; er[node] = sr; }
}

// ---------------- edge softmax: WAVE per node, lanes parallel over edges.
// Each alpha computed exactly ONCE (r12 lesson). Natural node order (r8 lesson).
__global__ void edge_softmax_w(const int* __restrict__ off, const int* __restrict__ esrc,
                               const float* __restrict__ el, const float* __restrict__ er,
                               float* __restrict__ alpha, int n) {
    int node = blockIdx.x * 4 + (threadIdx.x >> 6);
    if (node >= n) return;
    int lane = threadIdx.x & 63;
    int s = off[node], e = off[node + 1];
    int deg = e - s;
    if (deg <= 0) return;
    float erd = er[node];
    if (deg <= 64) {
        float v = -1e30f;
        if (lane < deg) {
            float t = el[esrc[s + lane]] + erd;
            v = t >= 0.f ? t : 0.2f * t;
        }
        float mx = v;
        #pragma unroll
        for (int o = 32; o > 0; o >>= 1) mx = fmaxf(mx, __shfl_xor(mx, o));
        float x = (lane < deg) ? __expf(v - mx) : 0.f;
        float ssum = x;
        #pragma unroll
        for (int o = 32; o > 0; o >>= 1) ssum += __shfl_xor(ssum, o);
        if (lane < deg) alpha[s + lane] = x / ssum;
    } else if (deg <= 256) {
        float v[4];
        float mx = -1e30f;
        #pragma unroll
        for (int r = 0; r < 4; r++) {
            v[r] = -1e30f;
            if (r * 64 + lane < deg) {
                float t = el[esrc[s + r * 64 + lane]] + erd;
                v[r] = t >= 0.f ? t : 0.2f * t;
            }
            mx = fmaxf(mx, v[r]);
        }
        #pragma unroll
        for (int o = 32; o > 0; o >>= 1) mx = fmaxf(mx, __shfl_xor(mx, o));
        float ssum = 0.f;
        #pragma unroll
        for (int r = 0; r < 4; r++) {
            v[r] = (r * 64 + lane < deg) ? __expf(v[r] - mx) : 0.f;
            ssum += v[r];
        }
        #pragma unroll
        for (int o = 32; o > 0; o >>= 1) ssum += __shfl_xor(ssum, o);
        float inv = 1.f / ssum;
        #pragma unroll
        for (int r = 0; r < 4; r++)
            if (r * 64 + lane < deg) alpha[s + r * 64 + lane] = v[r] * inv;
    } else if (lane == 0) {
        float mx = -1e30f;
        for (int j = s; j < e; j++) {
            float t = el[esrc[j]] + erd;
            t = t >= 0.f ? t : 0.2f * t;
            alpha[j] = t;
            mx = fmaxf(mx, t);
        }
        float ssum = 0.f;
        for (int j = s; j < e; j++) { float x = __expf(alpha[j] - mx); alpha[j] = x; ssum += x; }
        float inv = 1.f / ssum;
        for (int j = s; j < e; j++) alpha[j] *= inv;
    }
}

// ---------------- Y = A @ X, 64-ch chunks: eighth-wave (8 lanes x 16B) per node.
// chunk = blockIdx LSBs pins each 2.5MB X-slice to one XCD L2 (r8).
// 8-way edge unroll = 8x MLP on the ~200cy L2 chain (r13).
// perm==nullptr -> natural node order (1024-node last layer).
// Also zeros zbuf[0:zn) — producer-side zeroing.
__global__ void aggregate_e(const bf16* __restrict__ X, const float* __restrict__ alpha,
                            const int* __restrict__ esrc, const int* __restrict__ off,
                            const int* __restrict__ perm, float* __restrict__ zbuf, int zn,
                            bf16* __restrict__ Y, int din, int log2chunks, int nmax) {
    {
        int z = blockIdx.x * 256 + threadIdx.x;
        if (z < zn) zbuf[z] = 0.f;
    }
    int chunk = blockIdx.x & ((1 << log2chunks) - 1);
    int nb = blockIdx.x >> log2chunks;
    int sub = threadIdx.x >> 3, sl = threadIdx.x & 7;
    int slot = nb * 32 + sub;
    if (slot >= nmax) return;
    int node = perm ? perm[slot] : slot;
    const short* xb = (const short*)X + chunk * 64 + sl * 8;
    float acc[8] = {0.f,0.f,0.f,0.f,0.f,0.f,0.f,0.f};
    int s = off[node], e = off[node + 1];
    int j = s;
    for (; j + 8 <= e; j += 8) {
        float a[8]; int r[8]; bf16x8 w[8];
        #pragma unroll
        for (int q = 0; q < 8; q++) { a[q] = alpha[j + q]; r[q] = esrc[j + q]; }
        #pragma unroll
        for (int q = 0; q < 8; q++) w[q] = *(const bf16x8*)(xb + (long)r[q] * din);
        #pragma unroll
        for (int q = 0; q < 8; q++)
            #pragma unroll
            for (int v = 0; v < 8; v++) acc[v] += a[q] * bfbits2f(w[q][v]);
    }
    for (; j + 4 <= e; j += 4) {
        float a0 = alpha[j],     a1 = alpha[j + 1];
        float a2 = alpha[j + 2], a3 = alpha[j + 3];
        int r0 = esrc[j],     r1 = esrc[j + 1];
        int r2 = esrc[j + 2], r3 = esrc[j + 3];
        bf16x8 w0 = *(const bf16x8*)(xb + (long)r0 * din);
        bf16x8 w1 = *(const bf16x8*)(xb + (long)r1 * din);
        bf16x8 w2 = *(const bf16x8*)(xb + (long)r2 * din);
        bf16x8 w3 = *(const bf16x8*)(xb + (long)r3 * din);
        #pragma unroll
        for (int v = 0; v < 8; v++) acc[v] += a0 * bfbits2f(w0[v]);
        #pragma unroll
        for (int v = 0; v < 8; v++) acc[v] += a1 * bfbits2f(w1[v]);
        #pragma unroll
        for (int v = 0; v < 8; v++) acc[v] += a2 * bfbits2f(w2[v]);
        #pragma unroll
        for (int v = 0; v < 8; v++) acc[v] += a3 * bfbits2f(w3[v]);
    }
    for (; j < e; j++) {
        float a = alpha[j];
        bf16x8 w = *(const bf16x8*)(xb + (long)esrc[j] * din);
        #pragma unroll
        for (int v = 0; v < 8; v++) acc[v] += a * bfbits2f(w[v]);
    }
    short outv[8];
    #pragma unroll
    for (int v = 0; v < 8; v++) outv[v] = f2bfbits(acc[v]);
    bf16x8 store;
    __builtin_memcpy(&store, outv, sizeof(store));
    *(bf16x8*)((short*)Y + (long)node * din + chunk * 64 + sl * 8) = store;
}

// ---------------- L1-specialized GEMM: K=64, N=128 — no LDS, K in registers.
// r18 lesson: 128x128 tiling gives ncols=1 -> 160 blocks -> grid starvation
// (58 us for 0.33 GFLOP). Here: wave = 16 rows x 64 cols, 2500 waves = 625
// blocks. B (16 KB) is L2/L1-hot; fused bias+tanh+el/er (2 waves/row atomics).
__global__ __launch_bounds__(256, 4)
void gemm_k64(const bf16* __restrict__ A, const bf16* __restrict__ WT,
              const float* __restrict__ bias, bf16* __restrict__ C,
              const float* __restrict__ wal, const float* __restrict__ war,
              float* __restrict__ elp, float* __restrict__ erp) {
    int gw = blockIdx.x * 4 + (threadIdx.x >> 6);
    if (gw >= 2500) return;
    int r0 = (gw >> 1) << 4;          // 16-row tile
    int col0 = (gw & 1) << 6;         // 64-col half
    int lane = threadIdx.x & 63;
    int m = lane & 15, quad = lane >> 4;

    const short* Ab = (const short*)A + (long)(r0 + m) * 64 + quad * 8;
    bf16x8 a0 = *(const bf16x8*)(Ab);
    bf16x8 a1 = *(const bf16x8*)(Ab + 32);

    f32x4 acc[4];
    bf16x8 b0[4], b1[4];
    #pragma unroll
    for (int t = 0; t < 4; t++) {
        acc[t] = (f32x4){0.f, 0.f, 0.f, 0.f};
        const short* Bb = (const short*)WT + (long)(col0 + t * 16 + m) * 64 + quad * 8;
        b0[t] = *(const bf16x8*)(Bb);
        b1[t] = *(const bf16x8*)(Bb + 32);
    }
    #pragma unroll
    for (int t = 0; t < 4; t++) {
        acc[t] = __builtin_amdgcn_mfma_f32_16x16x32_bf16(a0, b0[t], acc[t], 0, 0, 0);
        acc[t] = __builtin_amdgcn_mfma_f32_16x16x32_bf16(a1, b1[t], acc[t], 0, 0, 0);
    }

    // epilogue: D row = r0 + quad*4 + r, col = col0 + 16t + m
    float sl4[4] = {0.f, 0.f, 0.f, 0.f};
    float sr4[4] = {0.f, 0.f, 0.f, 0.f};
    #pragma unroll
    for (int t = 0; t < 4; t++) {
        int col = col0 + t * 16 + m;
        float bb = bias[col];
        float wl = wal[col], wrr = war[col];
        #pragma unroll
        for (int r = 0; r < 4; r++) {
            float v = tanhf(acc[t][r] + bb);
            sl4[r] += v * wl;
            sr4[r] += v * wrr;
            float vn = __shfl_xor(v, 1);
            if ((m & 1) == 0) {
                unsigned int pk = (unsigned int)f2bfu(v) | ((unsigned int)f2bfu(vn) << 16);
                int row = r0 + quad * 4 + r;
                *(unsigned int*)((short*)C + (long)row * 128 + col) = pk;
            }
        }
    }
    #pragma unroll
    for (int r = 0; r < 4; r++) {
        float s1 = sl4[r], s2 = sr4[r];
        #pragma unroll
        for (int o = 1; o < 16; o <<= 1) {
            s1 += __shfl_xor(s1, o);
            s2 += __shfl_xor(s2, o);
        }
        if (m == 0) {
            int row = r0 + quad * 4 + r;
            atomicAdd(&elp[row], s1);     // 2 contending waves per row (col halves)
            atomicAdd(&erp[row], s2);
        }
    }
}

// ---------------- tiled GEMM: X_next = tanh(Y @ W + b), optional fused el/er
// 128x128 tile (r11: wider tiles starve block count), BK=64, global_load_lds w16,
// XOR bank swizzle, XCD-aware decode. LDS 32KB; epilogue aliased. (256,4):
// acc = 64 regs on unified file; (256,8) spills (r6).
__global__ __launch_bounds__(256, 4)
void gemm_tiled(const bf16* __restrict__ A, const bf16* __restrict__ WT,
                const float* __restrict__ bias, bf16* __restrict__ C,
                const float* __restrict__ wal, const float* __restrict__ war,
                float* __restrict__ elp, float* __restrict__ erp,
                int M, int K, int N, int ncols, int nrows) {
    __shared__ short smem[16384];   // As=smem[0:8192], Bs=smem[8192:16384]
    short* As = smem;
    short* Bs = smem + 8192;
    int g = blockIdx.x;
    int rowTile = ((g >> 3) / ncols) * 8 + (g & 7);
    int colTile = (g >> 3) % ncols;
    if (rowTile >= nrows) return;
    int row0 = rowTile << 7, col0 = colTile << 7;
    int tid = threadIdx.x;
    int lane = tid & 63, wave = tid >> 6;
    int wr = (wave >> 1) << 6;
    int wc = (wave & 1) << 6;
    int m = lane & 15, quad = lane >> 4;

    f32x4 acc[4][4];
    #pragma unroll
    for (int i = 0; i < 4; i++)
        #pragma unroll
        for (int j = 0; j < 4; j++) acc[i][j] = (f32x4){0.f, 0.f, 0.f, 0.f};

    const short* Ab = (const short*)A;
    const short* Bb = (const short*)WT;
    long ga[4], gb[4];
    #pragma unroll
    for (int n = 0; n < 4; n++) {
        int chunk = n * 256 + tid;
        int row = chunk >> 3;
        int qg = (chunk & 7) ^ (row & 7);
        ga[n] = (long)(row0 + row) * K + qg * 8;
        gb[n] = (long)(col0 + row) * K + qg * 8;
    }

    typedef const __attribute__((address_space(1))) void cgvoid;
    typedef __attribute__((address_space(3))) void lvoid;

    for (int k0 = 0; k0 < K; k0 += 64) {
        __syncthreads();
        #pragma unroll
        for (int n = 0; n < 4; n++)
            __builtin_amdgcn_global_load_lds((cgvoid*)(Ab + ga[n] + k0),
                                             (lvoid*)(As + (n * 256 + tid) * 8), 16, 0, 0);
        #pragma unroll
        for (int n = 0; n < 4; n++)
            __builtin_amdgcn_global_load_lds((cgvoid*)(Bb + gb[n] + k0),
                                             (lvoid*)(Bs + (n * 256 + tid) * 8), 16, 0, 0);
        __syncthreads();
        #pragma unroll
        for (int h = 0; h < 2; h++) {
            bf16x8 af[4], bfr[4];
            #pragma unroll
            for (int s = 0; s < 4; s++) {
                int ra = wr + s * 16 + m;
                int sa = (h * 4 + quad) ^ (ra & 7);
                af[s] = *(const bf16x8*)(As + ra * 64 + sa * 8);
                int rb = wc + s * 16 + m;
                int sb = (h * 4 + quad) ^ (rb & 7);
                bfr[s] = *(const bf16x8*)(Bs + rb * 64 + sb * 8);
            }
            #pragma unroll
            for (int i = 0; i < 4; i++)
                #pragma unroll
                for (int j = 0; j < 4; j++)
                    acc[i][j] = __builtin_amdgcn_mfma_f32_16x16x32_bf16(af[i], bfr[j], acc[i][j], 0, 0, 0);
        }
    }

    // ---- epilogue: bias+tanh (+fused el/er partials), LDS round-trip, b128 stores
    float bb[4], walr[4], warr[4];
    #pragma unroll
    for (int j = 0; j < 4; j++) {
        int col = col0 + wc + j * 16 + m;
        bb[j] = bias[col];
        if (elp) { walr[j] = wal[col]; warr[j] = war[col]; }
    }
    __syncthreads();                      // all waves done reading As/Bs
    short* myep = smem + wave * 1152;     // 16 rows x stride 72 shorts per wave
    #pragma unroll
    for (int i = 0; i < 4; i++) {
        float sl4[4] = {0.f, 0.f, 0.f, 0.f};
        float sr4[4] = {0.f, 0.f, 0.f, 0.f};
        #pragma unroll
        for (int j = 0; j < 4; j++) {
            #pragma unroll
            for (int r = 0; r < 4; r++) {
                float v = tanhf(acc[i][j][r] + bb[j]);
                if (elp) { sl4[r] += v * walr[j]; sr4[r] += v * warr[j]; }
                float vn = __shfl_xor(v, 1);
                if ((m & 1) == 0) {
                    unsigned int pk = (unsigned int)f2bfu(v) | ((unsigned int)f2bfu(vn) << 16);
                    *(unsigned int*)(myep + (quad * 4 + r) * 72 + j * 16 + m) = pk;
                }
            }
        }
        #pragma unroll
        for (int pass = 0; pass < 2; pass++) {
            int lr = pass * 8 + (lane >> 3);
            int lc = (lane & 7) * 8;
            bf16x8 v = *(const bf16x8*)(myep + lr * 72 + lc);
            int row = row0 + wr + i * 16 + lr;
            if (row < M)
                *(bf16x8*)((short*)C + (long)row * N + col0 + wc + lc) = v;
        }
        if (elp) {
            #pragma unroll
            for (int r = 0; r < 4; r++) {
                float s1 = sl4[r], s2 = sr4[r];
                #pragma unroll
                for (int o = 1; o < 16; o <<= 1) {
                    s1 += __shfl_xor(s1, o);
                    s2 += __shfl_xor(s2, o);
                }
                if (m == 0) {
                    int row = row0 + wr + i * 16 + quad * 4 + r;
                    if (row < M) {
                        atomicAdd(&elp[row], s1);
                        atomicAdd(&erp[row], s2);
                    }
                }
            }
        }
    }
}

// ---------------- pool sum: 256 blocks (r15 lesson: narrow head = latency collapse)
__global__ void pool_sum(const bf16* __restrict__ X, const int* __restrict__ order,
                         float* __restrict__ poolsum) {
    int cg = blockIdx.x & 3, rs = blockIdx.x >> 2;
    int c = cg * 256 + threadIdx.x;
    int rows = order[0] + 1;
    float s = 0.f;
    for (int r = rs; r < rows; r += 64) s += b2f(X[(long)r * 1024 + c]);
    atomicAdd(&poolsum[c], s);
}

// ---------------- head ----------------
__global__ void head_logits(const float* __restrict__ poolsum, const float* __restrict__ relW,
                            const float* __restrict__ relB, const int* __restrict__ order,
                            float* __restrict__ logits) {
    int t = blockIdx.x;
    float s = 0.f;
    for (int c = threadIdx.x; c < 1024; c += 256)
        s += poolsum[c] * relW[(long)c * 64 + t];
    __shared__ float sb[256];
    sb[threadIdx.x] = s;
    __syncthreads();
    for (int st = 128; st > 0; st >>= 1) {
        if (threadIdx.x < st) sb[threadIdx.x] += sb[threadIdx.x + st];
        __syncthreads();
    }
    if (threadIdx.x == 0) {
        float rows = (float)(order[0] + 1);
        logits[t] = sb[0] / rows + relB[t];
    }
}

__global__ void head_gather(const float* __restrict__ logits, const int* __restrict__ rel,
                            float* __restrict__ out) {
    __shared__ int nzv[64];
    int t = threadIdx.x;
    if (t == 0) {
        int k = 0;
        for (int i = 0; i < 64; i++)
            if (rel[i] != 0) nzv[k++] = i;
        for (; k < 64; k++) nzv[k] = 0;
    }
    __syncthreads();
    out[t] = logits[nzv[t]];
}

extern "C" void kernel_launch(void* const* d_in, const int* in_sizes, int n_in,
                              void* d_out, int out_size, void* d_ws, size_t ws_size,
                              hipStream_t stream) {
    const float* feat = (const float*)d_in[0];
    const float* W[4]  = {(const float*)d_in[1], (const float*)d_in[5], (const float*)d_in[9],  (const float*)d_in[13]};
    const float* al[4] = {(const float*)d_in[2], (const float*)d_in[6], (const float*)d_in[10], (const float*)d_in[14]};
    const float* ar[4] = {(const float*)d_in[3], (const float*)d_in[7], (const float*)d_in[11], (const float*)d_in[15]};
    const float* bias[4] = {(const float*)d_in[4], (const float*)d_in[8], (const float*)d_in[12], (const float*)d_in[16]};
    const float* relW = (const float*)d_in[17];
    const float* relB = (const float*)d_in[18];
    const int* src = (const int*)d_in[19];
    const int* dst = (const int*)d_in[20];
    const int* rel = (const int*)d_in[21];
    const int* order = (const int*)d_in[22];

    const int dims[5] = {64, 128, 256, 512, 1024};

    char* p = (char*)d_ws;
    auto carve = [&](size_t bytes) {
        void* r = (void*)p;
        p += (bytes + 255) & ~(size_t)255;
        return r;
    };
    bf16* xbuf = (bf16*)carve((size_t)MPAD * 1024 * sizeof(bf16));
    bf16* ybuf = (bf16*)carve((size_t)MPAD * 512 * sizeof(bf16));
    bf16* featb = (bf16*)carve((size_t)MPAD * 64 * sizeof(bf16));
    bf16* wt[4];
    for (int l = 0; l < 4; l++)
        wt[l] = (bf16*)carve((size_t)dims[l] * dims[l + 1] * sizeof(bf16));
    float* walbuf = (float*)carve(4 * 512 * sizeof(float));
    float* warbuf = (float*)carve(4 * 512 * sizeof(float));
    float* elbuf[2];
    elbuf[0] = (float*)carve((size_t)2 * NN * sizeof(float));   // el | er
    elbuf[1] = (float*)carve((size_t)2 * NN * sizeof(float));
    float* alpha = (float*)carve((size_t)NE * sizeof(float));
    int* counts  = (int*)carve((size_t)NN * sizeof(int));
    int* offsets = (int*)carve((size_t)(NN + 1) * sizeof(int));
    int* cursor  = (int*)carve((size_t)NN * sizeof(int));
    int* esrc    = (int*)carve((size_t)NE * sizeof(int));
    int* nodeperm = (int*)carve((size_t)NN * sizeof(int));
    int* blocksums = (int*)carve((size_t)NB * sizeof(int));
    int* hglob   = (int*)carve(256 * sizeof(int));
    int* curg    = (int*)carve(256 * sizeof(int));
    float* poolsum = (float*)carve(1024 * sizeof(float));
    float* logits  = (float*)carve(64 * sizeof(float));

    // ---- 1: setup (wal/war + convert/transpose + counts/h zero) ----
    setup_all<<<960 + 7720, 256, 0, stream>>>(
        feat, W[0], al[0], ar[0], W[1], al[1], ar[1],
        W[2], al[2], ar[2], W[3], al[3], ar[3],
        featb, wt[0], wt[1], wt[2], wt[3], counts, hglob, walbuf, warbuf);

    // ---- 2-5: CSR (wide scan) + degree sort + scatter + layer-1 el/er ----
    hist_kernel<<<(NE + 255) / 256, 256, 0, stream>>>(dst, counts, NE);
    csr_phase1<<<NB, 256, 0, stream>>>(counts, blocksums, hglob);
    csr_phase2<<<NB + 1, 256, 0, stream>>>(counts, blocksums, offsets, cursor, hglob, curg);
    scatter_elr<<<1250 + NB + 5000, 256, 0, stream>>>(src, dst, cursor, esrc,
                                                      counts, curg, nodeperm,
                                                      featb, walbuf, warbuf,
                                                      elbuf[0], elbuf[0] + NN);

    const bf16* x = featb;
    const int nrows = MPAD / 128;     // 157
    const int nrowsPad = 160;
    const int log2c[4] = {0, 1, 2, 3};   // chunks = din/64
    for (int l = 0; l < 4; l++) {
        int K = dims[l], N = dims[l + 1];
        float* elr_rd = elbuf[l & 1];
        float* elr_wr = elbuf[(l + 1) & 1];
        // Last layer: only rows 0..ORD-1 feed the pooling head (order=1023).
        int nsm   = (l < 3) ? NN : ORD;
        int nmax  = (l < 3) ? NN : ORD;
        int nodeBlocks = (nmax + 31) / 32;            // 625 or 32
        const int* aggPerm = (l < 3) ? nodeperm : nullptr;
        edge_softmax_w<<<(nsm + 3) / 4, 256, 0, stream>>>(offsets, esrc, elr_rd,
                                                          elr_rd + NN, alpha, nsm);
        float* zbuf = (l < 3) ? elr_wr : poolsum;
        int zn = (l < 3) ? 2 * NN : 1024;
        aggregate_e<<<nodeBlocks << log2c[l], 256, 0, stream>>>(
            x, alpha, esrc, offsets, aggPerm, zbuf, zn, ybuf, K, log2c[l], nmax);
        int ncols = N >> 7;
        if (l == 0) {
            gemm_k64<<<625, 256, 0, stream>>>(ybuf, wt[0], bias[0], xbuf,
                                              walbuf + 512, warbuf + 512,
                                              elr_wr, elr_wr + NN);
        } else if (l < 3) {
            gemm_tiled<<<nrowsPad * ncols, 256, 0, stream>>>(
                ybuf, wt[l], bias[l], xbuf,
                walbuf + (l + 1) * 512, warbuf + (l + 1) * 512,
                elr_wr, elr_wr + NN,
                NN, K, N, ncols, nrows);
        } else {
            gemm_tiled<<<8 * ncols, 256, 0, stream>>>(
                ybuf, wt[l], bias[l], xbuf,
                nullptr, nullptr, nullptr, nullptr,
                ORD, K, N, ncols, 8);
        }
        x = xbuf;
    }

    // ---- head (poolsum zeroed by L4 aggregate; wide 256-block pool) ----
    pool_sum<<<256, 256, 0, stream>>>(xbuf, order, poolsum);
    head_logits<<<64, 256, 0, stream>>>(poolsum, relW, relB, order, logits);
    head_gather<<<1, 64, 0, stream>>>(logits, rel, (float*)d_out);
}